// Round 1
// baseline (307.154 us; speedup 1.0000x reference)
//
#include <hip/hip_runtime.h>
#include <hip/hip_fp16.h>

#define NN 50000
#define NE 800000
#define SN (2 * NN)   // 100000 bins: [0,NN)=dst per node, [NN,2NN)=src per node
#define NXCD 8

__device__ __forceinline__ float sigm(float v) { return 1.0f / (1.0f + __expf(-v)); }

// ===========================================================================
// build_ranks: per-XCD partitioned counters + workgroup-scope relaxed atomics.
// Theory: device-scope atomics write through to the memory side (measured:
// WRITE_SIZE = 1.6M x 32B sectors, 23.5 Gop/s). With cntX[xcd][bin], every
// RMW to a given counter copy comes from one XCD, so a workgroup-scope atomic
// (no sc1) is sufficient and should execute as an XCD-local L2 RMW.
// Rank packed as (xcd<<12 | local_rank); local_rank <= degree (~50) << 4096.
// ===========================================================================
__global__ void build_ranks(const int* __restrict__ ei,
                            int* __restrict__ cntX,
                            unsigned short* __restrict__ rank_s,
                            unsigned short* __restrict__ rank_d)
{
    unsigned xcd;
    asm volatile("s_getreg_b32 %0, hwreg(HW_REG_XCC_ID, 0, 32)" : "=s"(xcd));
    xcd &= 7;
    int e = blockIdx.x * 256 + threadIdx.x;   // NE == 3125*256 exactly
    int s = ei[e], d = ei[NE + e];
    int* base = cntX + xcd * SN;
    unsigned rd = (unsigned)__hip_atomic_fetch_add(base + d, 1,
                        __ATOMIC_RELAXED, __HIP_MEMORY_SCOPE_WORKGROUP);
    unsigned rs = (unsigned)__hip_atomic_fetch_add(base + NN + s, 1,
                        __ATOMIC_RELAXED, __HIP_MEMORY_SCOPE_WORKGROUP);
    rank_d[e] = (unsigned short)((xcd << 12) | rd);
    rank_s[e] = (unsigned short)((xcd << 12) | rs);
}

// ===========================================================================
// scan_k1: per bin, 8-way exclusive prefix across the XCD copies (written
// back in place -> per-XCD base for build_perm), total -> cnt_tot; then the
// usual block-sum reduce. Indexing switched to q*256+t for coalescing (only
// the block SUM matters here, order within the 2048-bin range is free).
// ===========================================================================
__global__ void scan_k1(int* __restrict__ cntX, int* __restrict__ cnt_tot,
                        int n, int* __restrict__ bsum)
{
    __shared__ int sm[256];
    int t = threadIdx.x;
    int base = blockIdx.x * 2048;
    int sum = 0;
#pragma unroll
    for (int q = 0; q < 8; ++q) {
        int idx = base + q * 256 + t;
        if (idx < n) {
            int run = 0;
#pragma unroll
            for (int x = 0; x < NXCD; ++x) {
                int c = cntX[x * SN + idx];
                cntX[x * SN + idx] = run;   // exclusive per-XCD base
                run += c;
            }
            cnt_tot[idx] = run;
            sum += run;
        }
    }
    sm[t] = sum;
    __syncthreads();
#pragma unroll
    for (int d = 128; d; d >>= 1) { if (t < d) sm[t] += sm[t + d]; __syncthreads(); }
    if (t == 0) bsum[blockIdx.x] = sm[0];
}

__global__ void scan_k3(const int* __restrict__ cnt, int n,
                        const int* __restrict__ bsum, int nb,
                        int* __restrict__ offset)
{
    __shared__ int s[256];
    __shared__ int sb[64];
    int t = threadIdx.x;
    if (t < 64) sb[t] = (t < nb) ? bsum[t] : 0;
    int base = blockIdx.x * 2048 + t * 8;
    int v[8]; int sum = 0;
#pragma unroll
    for (int q = 0; q < 8; ++q) {
        int idx = base + q;
        v[q] = (idx < n) ? cnt[idx] : 0;
        sum += v[q];
    }
    s[t] = sum;
    __syncthreads();
    if (t == 0) {             // exclusive scan of 49 block sums (trivial)
        int run = 0;
        for (int i = 0; i < nb; ++i) { int x = sb[i]; sb[i] = run; run += x; }
    }
#pragma unroll
    for (int d = 1; d < 256; d <<= 1) {
        int a = (t >= d) ? s[t - d] : 0;
        __syncthreads();
        s[t] += a;
        __syncthreads();
    }
    int run = sb[blockIdx.x] + ((t > 0) ? s[t - 1] : 0);
#pragma unroll
    for (int q = 0; q < 8; ++q) {
        int idx = base + q;
        if (idx <= n) offset[idx] = run;
        run += v[q];
    }
}

// ===========================================================================
// build_perm: global rank = per-XCD exclusive base (cntX after scan_k1) +
// local rank. One 8B scattered store per edge, as before.
// sperm64[spos] = {sl:4 | dstpos:20 | e:20}; sl = s&15 (blocks 16-aligned).
// ===========================================================================
__global__ void build_perm(const int* __restrict__ ei,
                           const int* __restrict__ off_all,
                           const unsigned short* __restrict__ rank_s,
                           const unsigned short* __restrict__ rank_d,
                           const int* __restrict__ cntX,
                           unsigned long long* __restrict__ sperm64)
{
    int e = blockIdx.x * 256 + threadIdx.x;
    int s = ei[e], d = ei[NE + e];
    unsigned prs = rank_s[e], prd = rank_d[e];
    int spos = off_all[NN + s] - NE
             + cntX[(int)(prs >> 12) * SN + NN + s] + (int)(prs & 0xFFFu);
    int dp   = off_all[d]
             + cntX[(int)(prd >> 12) * SN + d]      + (int)(prd & 0xFFFu);
    sperm64[spos] = ((unsigned long long)(s & 15) << 40)
                  | ((unsigned long long)(unsigned)dp << 20)
                  | (unsigned long long)(unsigned)e;
}

// ===========================================================================
// edge_fusedG<DIN>: block = out-edges of src nodes [16b,16b+16) (src-CSR).
// Phase 1: G for these 16 nodes INTO LDS from LDS-staged w2.
// Phase 2: chunked edge loop; msg computed fp32, stored fp16 (32B rows =
// TCC write granule, full-sector stores). 8 lanes/row pack __half2.
// ===========================================================================
template<int DIN>
__global__ __launch_bounds__(256) void edge_fusedG(
        const float* __restrict__ xin,    // [NN][DIN]
        const unsigned long long* __restrict__ sperm64, // [NE] src-sorted
        const float* __restrict__ ea,     // [NE][4] original order
        const float* __restrict__ eW1,    // [4][16]
        const float* __restrict__ eb1,    // [16]
        const float* __restrict__ eW2,    // [16][DIN*16]
        const float* __restrict__ eb2,    // [DIN*16]
        const int*   __restrict__ off_all,// src CSR at off_all[NN+s]
        __half* __restrict__ msgbuf)      // [NE][16] fp16 dst-sorted rows
{
    constexpr int MROW = 260;
    constexpr int W2B  = DIN * 16 * 20 * 4;           // w2L bytes (phase 1)
    constexpr int SMB  = 16 * MROW * 4 + 256 * 4;     // smemM + sdp (phase 2)
    constexpr int UNIB = (W2B > SMB) ? W2B : SMB;
    __shared__ __align__(16) char uni[UNIB];
    float* w2L   = (float*)uni;                        // [(i*16+k)*20 + o]
    float* smemM = (float*)uni;                        // [16][MROW]
    int*   sdp   = (int*)(uni + 16 * MROW * 4);        // [256]
    __shared__ __align__(16) float4 G4[16 * 69];       // [sl*69 + ob*17 + k]
    __shared__ __align__(16) float4 xbL[16 * 5];       // [sl*5 + ob] (pad 5)
    __shared__ __align__(16) float  xL[16 * DIN];
    __shared__ __align__(16) float  b2L[DIN * 16];
    __shared__ __align__(16) float4 w1t[16];
    __shared__ __align__(16) float  b1s[16];

    int tid = threadIdx.x;
    int nb  = blockIdx.x * 16;                // first src node of block
    if (tid < 16) {
        w1t[tid] = make_float4(eW1[tid], eW1[16 + tid], eW1[32 + tid], eW1[48 + tid]);
        b1s[tid] = eb1[tid];
    }
    for (int t = tid; t < 16 * DIN * 16; t += 256) {
        int k = t / (DIN * 16);
        int rem = t - k * DIN * 16;
        int i = rem >> 4, o = rem & 15;
        w2L[(i * 16 + k) * 20 + o] = eW2[t];
    }
    for (int t = tid; t < DIN * 16; t += 256) b2L[t] = eb2[t];
    for (int t = tid; t < 16 * DIN; t += 256) xL[t] = xin[(size_t)nb * DIN + t];
    __syncthreads();

    // ---- phase 1: G + xb for 16 local nodes; thread (nl, k) ----
    {
        int nl = tid >> 4, k = tid & 15;
        const float* xrow = xL + nl * DIN;
#pragma unroll
        for (int ob = 0; ob < 4; ++ob) {
            float4 a4 = make_float4(0.f, 0.f, 0.f, 0.f);
#pragma unroll
            for (int i = 0; i < DIN; ++i) {
                const float4 w = *((const float4*)(w2L + (i * 16 + k) * 20) + ob);
                a4.x += xrow[i] * w.x; a4.y += xrow[i] * w.y;
                a4.z += xrow[i] * w.z; a4.w += xrow[i] * w.w;
            }
            G4[nl * 69 + ob * 17 + k] = a4;
        }
        if (k < 4) {
            int ob = k;
            const float4* b2v = (const float4*)b2L;
            float4 a4 = make_float4(0.f, 0.f, 0.f, 0.f);
#pragma unroll
            for (int i = 0; i < DIN; ++i) {
                float4 b = b2v[i * 4 + ob];
                a4.x += xrow[i] * b.x; a4.y += xrow[i] * b.y;
                a4.z += xrow[i] * b.z; a4.w += xrow[i] * b.w;
            }
            xbL[nl * 5 + ob] = a4;
        }
    }
    __syncthreads();   // w2L dead; uni becomes smemM/sdp

    // ---- phase 2: chunked edge loop over this block's src-CSR range ----
    int eBeg = off_all[NN + nb] - NE;
    int eEnd = off_all[NN + nb + 16] - NE;
    for (int cb = eBeg; cb < eEnd; cb += 256) {
        int pos = cb + tid;
        bool valid = pos < eEnd;
        unsigned long long pk = valid ? sperm64[pos] : 0ull;
        int e  = (int)(pk & 0xFFFFFu);
        int dp = (int)((pk >> 20) & 0xFFFFFu);
        int sl = (int)(pk >> 40);
        float4 a = valid ? ((const float4*)ea)[e] : make_float4(0.f, 0.f, 0.f, 0.f);

        float h[16];
#pragma unroll
        for (int j = 0; j < 16; ++j) {
            float4 w = w1t[j];
            float p = b1s[j] + a.x * w.x + a.y * w.y + a.z * w.z + a.w * w.w;
            h[j] = p * sigm(p);
        }
        float4 acc[4];
#pragma unroll
        for (int ob = 0; ob < 4; ++ob) acc[ob] = xbL[sl * 5 + ob];
#pragma unroll
        for (int k = 0; k < 16; ++k) {
            float hk = h[k];
#pragma unroll
            for (int ob = 0; ob < 4; ++ob) {
                float4 g = G4[sl * 69 + ob * 17 + k];
                acc[ob].x += hk * g.x; acc[ob].y += hk * g.y;
                acc[ob].z += hk * g.z; acc[ob].w += hk * g.w;
            }
        }
        sdp[tid] = valid ? dp : -1;
#pragma unroll
        for (int ob = 0; ob < 4; ++ob) {
            smemM[(ob * 4 + 0) * MROW + tid] = acc[ob].x;
            smemM[(ob * 4 + 1) * MROW + tid] = acc[ob].y;
            smemM[(ob * 4 + 2) * MROW + tid] = acc[ob].z;
            smemM[(ob * 4 + 3) * MROW + tid] = acc[ob].w;
        }
        __syncthreads();
        // 8 lanes per row: lane packs channels (2p, 2p+1) into one __half2.
#pragma unroll
        for (int r = 0; r < 8; ++r) {
            int le = r * 32 + (tid >> 3);          // 32 rows per round
            int p  = tid & 7;
            int d2 = sdp[le];                      // 8-lane broadcast
            float v0 = smemM[(2 * p)     * MROW + le];
            float v1 = smemM[(2 * p + 1) * MROW + le];
            if (d2 >= 0) {
                __half2 hv = __floats2half2_rn(v0, v1);
                *((__half2*)(msgbuf + (size_t)d2 * 16) + p) = hv;  // 32B rows
            }
        }
        __syncthreads();
    }
}

// ===========================================================================
// Gather helper: 16-lane group per node; lanes 0-7 read row j (__half2 each),
// lanes 8-15 read row j+1 -> 64B contiguous per group per iteration, half
// the iterations; shfl_xor(8) merges halves, 2 shuffles redistribute to
// per-channel layout. fp32 accumulation throughout.
// ===========================================================================
__device__ __forceinline__ float gather_msg16(const __half* __restrict__ msgbuf,
                                              int s0, int e0, int tid)
{
    int half = (tid >> 3) & 1;
    int p    = tid & 7;
    float ax = 0.f, ay = 0.f;
    for (int j = s0 + half; j < e0; j += 2) {
        __half2 hv = *((const __half2*)(msgbuf + (size_t)j * 16) + p);
        float2 f = __half22float2(hv);
        ax += f.x; ay += f.y;
    }
    ax += __shfl_xor(ax, 8, 16);
    ay += __shfl_xor(ay, 8, 16);
    int ch = tid & 15;
    float vx = __shfl(ax, ch >> 1, 16);
    float vy = __shfl(ay, ch >> 1, 16);
    return (ch & 1) ? vy : vx;
}

// ===========================================================================
// gather_L0: tiny-LDS, high-occupancy; fp16 msg rows, fp32 accumulation.
// ===========================================================================
__global__ __launch_bounds__(256) void gather_L0(
        const float* __restrict__ xin,    // [NN][8]
        const float* __restrict__ root,   // [8][16]
        const float* __restrict__ bias,   // [16]
        const int*   __restrict__ off_all,
        const __half* __restrict__ msgbuf,
        float* __restrict__ x1)           // [NN][16]
{
    __shared__ __align__(16) float rootL[8 * 16];
    __shared__ __align__(16) float biasL[16];
    int tid = threadIdx.x;
    if (tid < 128) rootL[tid] = root[tid];
    if (tid < 16) biasL[tid] = bias[tid];
    __syncthreads();

    int ch = tid & 15;
    int n  = blockIdx.x * 16 + (tid >> 4);
    int s0 = off_all[n], e0 = off_all[n + 1];

    float acc = gather_msg16(msgbuf, s0, e0, tid);
    float v = acc / fmaxf((float)(e0 - s0), 1.0f) + biasL[ch];
#pragma unroll
    for (int i = 0; i < 8; ++i)
        v += xin[(size_t)n * 8 + i] * rootL[i * 16 + ch];
    x1[(size_t)n * 16 + ch] = fmaxf(v, 0.f);
}

// ===========================================================================
// gather_final: fp16 msg rows + node update + output MLP.
// ===========================================================================
__global__ __launch_bounds__(256) void gather_final(
        const float* __restrict__ x1,     // [NN][16]
        const float* __restrict__ root,   // [16][16]
        const float* __restrict__ bias,   // [16]
        const int*   __restrict__ off_all,
        const __half* __restrict__ msgbuf,
        const float* __restrict__ mW1,    // [16][16]
        const float* __restrict__ mb1,    // [16]
        const float* __restrict__ mW2,    // [16]
        const float* __restrict__ mb2,    // [1]
        float* __restrict__ out)          // [NN]
{
    __shared__ __align__(16) float rootL[256];
    __shared__ __align__(16) float biasL[16];
    __shared__ __align__(16) float w1m[256];
    __shared__ __align__(16) float b1m[16];
    __shared__ __align__(16) float w2m[16];
    __shared__ float b2m;
    int tid = threadIdx.x;
    rootL[tid] = root[tid];
    w1m[tid] = mW1[tid];
    if (tid < 16) { biasL[tid] = bias[tid]; b1m[tid] = mb1[tid]; w2m[tid] = mW2[tid]; }
    if (tid == 0) b2m = mb2[0];
    __syncthreads();

    int ch = tid & 15;
    int n  = blockIdx.x * 16 + (tid >> 4);
    int s0 = off_all[n], e0 = off_all[n + 1];

    float acc = gather_msg16(msgbuf, s0, e0, tid);
    float v = acc / fmaxf((float)(e0 - s0), 1.0f) + biasL[ch];
#pragma unroll
    for (int i = 0; i < 16; ++i)
        v += x1[(size_t)n * 16 + i] * rootL[i * 16 + ch];
    v = fmaxf(v, 0.f);

    float z = b1m[ch];
#pragma unroll
    for (int o = 0; o < 16; ++o) {
        float vo = __shfl(v, o, 16);
        z += vo * w1m[o * 16 + ch];
    }
    float ss = z * sigm(z) * w2m[ch];
#pragma unroll
    for (int off = 8; off; off >>= 1) ss += __shfl_xor(ss, off, 16);
    if (ch == 0) out[n] = sigm(ss + b2m);
}

// ===========================================================================
// Host launch
// ===========================================================================
extern "C" void kernel_launch(void* const* d_in, const int* in_sizes, int n_in,
                              void* d_out, int out_size, void* d_ws, size_t ws_size,
                              hipStream_t stream) {
    const float* x     = (const float*)d_in[0];
    const int*   ei    = (const int*)  d_in[1];
    const float* ea    = (const float*)d_in[2];
    const float* eW1_0 = (const float*)d_in[3];
    const float* eb1_0 = (const float*)d_in[4];
    const float* eW2_0 = (const float*)d_in[5];
    const float* eb2_0 = (const float*)d_in[6];
    const float* root0 = (const float*)d_in[7];
    const float* bias0 = (const float*)d_in[8];
    const float* eW1_1 = (const float*)d_in[9];
    const float* eb1_1 = (const float*)d_in[10];
    const float* eW2_1 = (const float*)d_in[11];
    const float* eb2_1 = (const float*)d_in[12];
    const float* root1 = (const float*)d_in[13];
    const float* bias1 = (const float*)d_in[14];
    const float* mW1   = (const float*)d_in[15];
    const float* mb1   = (const float*)d_in[16];
    const float* mW2   = (const float*)d_in[17];
    const float* mb2   = (const float*)d_in[18];
    float* out = (float*)d_out;

    const int EG = NE / 256;   // 3125
    const int GG = NN / 16;    // 3125
    const int SB = (SN + 2047) / 2048;  // 49

    // ---- ws layout (4B words) ----
    int* W = (int*)d_ws;
    int*   off_all = W;                       // 100001 -> pad 100004
    int*   bsum    = W + 100004;              // 512
    unsigned short* rank_s = (unsigned short*)(W + 100516);  // NE u16
    unsigned short* rank_d = (unsigned short*)(W + 500516);  // NE u16
    unsigned long long* sperm64 = (unsigned long long*)(W + 900516); // NE u64
    float*  x1     = (float*)(W + 2500516);   // [NN][16]
    __half* msgbuf = (__half*)(W + 3300516);  // [NE][16] fp16 = 6.4M words
    int*    cntX   = W + 3300516;             // 8*SN ints, overlaid on msgbuf
    int*    cnt_tot= W + 3300516 + NXCD * SN; // SN ints, overlaid on msgbuf

    hipMemsetAsync(cntX, 0, (size_t)NXCD * SN * sizeof(int), stream);
    build_ranks<<<EG, 256, 0, stream>>>(ei, cntX, rank_s, rank_d);
    scan_k1<<<SB, 256, 0, stream>>>(cntX, cnt_tot, SN, bsum);
    scan_k3<<<SB, 256, 0, stream>>>(cnt_tot, SN, bsum, SB, off_all);
    build_perm<<<EG, 256, 0, stream>>>(ei, off_all, rank_s, rank_d, cntX, sperm64);

    // ---- layer 0 ----
    edge_fusedG<8><<<GG, 256, 0, stream>>>(x, sperm64, ea, eW1_0, eb1_0,
                                           eW2_0, eb2_0, off_all, msgbuf);
    gather_L0<<<GG, 256, 0, stream>>>(x, root0, bias0, off_all, msgbuf, x1);

    // ---- layer 1 ----
    edge_fusedG<16><<<GG, 256, 0, stream>>>(x1, sperm64, ea, eW1_1, eb1_1,
                                            eW2_1, eb2_1, off_all, msgbuf);
    gather_final<<<GG, 256, 0, stream>>>(x1, root1, bias1, off_all, msgbuf,
                                         mW1, mb1, mW2, mb2, out);
}

// Round 2
// 292.605 us; speedup vs baseline: 1.0497x; 1.0497x over previous
//
#include <hip/hip_runtime.h>
#include <hip/hip_fp16.h>

#define NN 50000
#define NE 800000
#define NBUCK 196          // ceil(NN/256) buckets of 256 node-ids each

__device__ __forceinline__ float sigm(float v) { return 1.0f / (1.0f + __expf(-v)); }

// ===========================================================================
// Sort-based CSR construction (replaces build_ranks + scans + build_perm).
// Mechanism: uniform-random returning atomics pay ~32B memory-side sector per
// op at ~25.4 G/s (measured R0/R1, WRITE_SIZE=53MB). A 2-level bucket sort
// makes every scatter block-LOCAL (per-block runs into per-bucket regions),
// so L2 write-back merges runs into full lines: scatter cost ~= payload BW.
// ===========================================================================

// ---- stage 0: global per-bucket counts for dst (A) and src (B) ----
__global__ void sort_count(const int* __restrict__ ei,
                           int* __restrict__ cntA, int* __restrict__ cntB)
{
    __shared__ int hA[NBUCK], hB[NBUCK];
    int t = threadIdx.x;
    for (int i = t; i < NBUCK; i += 256) { hA[i] = 0; hB[i] = 0; }
    __syncthreads();
    int base = blockIdx.x * 2048;
#pragma unroll
    for (int r = 0; r < 8; ++r) {
        int idx = base + r * 256 + t;
        if (idx < NE) {
            int s = ei[idx], d = ei[NE + idx];
            atomicAdd(&hB[s >> 8], 1);
            atomicAdd(&hA[d >> 8], 1);
        }
    }
    __syncthreads();
    for (int i = t; i < NBUCK; i += 256) {
        if (hA[i]) atomicAdd(&cntA[i], hA[i]);
        if (hB[i]) atomicAdd(&cntB[i], hB[i]);
    }
}

// ---- exclusive scan of the 196 bucket counts (A and B), init cursors ----
__global__ void sort_scan(const int* __restrict__ cntA, const int* __restrict__ cntB,
                          int* __restrict__ baseA, int* __restrict__ baseB,
                          int* __restrict__ curA,  int* __restrict__ curB)
{
    __shared__ int a[256], b[256];
    int t = threadIdx.x;
    a[t] = (t < NBUCK) ? cntA[t] : 0;
    b[t] = (t < NBUCK) ? cntB[t] : 0;
    __syncthreads();
#pragma unroll
    for (int dd = 1; dd < 256; dd <<= 1) {
        int av = (t >= dd) ? a[t - dd] : 0;
        int bv = (t >= dd) ? b[t - dd] : 0;
        __syncthreads();
        a[t] += av; b[t] += bv;
        __syncthreads();
    }
    int exA = (t > 0) ? a[t - 1] : 0;
    int exB = (t > 0) ? b[t - 1] : 0;
    if (t < NBUCK) { baseA[t] = exA; curA[t] = exA; baseB[t] = exB; curB[t] = exB; }
    if (t == 255)  { baseA[NBUCK] = a[255]; baseB[NBUCK] = b[255]; }  // == NE
}

// ---- stage 1A: scatter (d&255, e) records into dst-buckets (run-claimed) ----
__global__ __launch_bounds__(256) void sort_scatterA(const int* __restrict__ ei,
                                                     int* __restrict__ curA,
                                                     unsigned* __restrict__ recA)
{
    __shared__ int lcnt[NBUCK];
    __shared__ int lofs[NBUCK];
    int t = threadIdx.x;
    for (int i = t; i < NBUCK; i += 256) lcnt[i] = 0;
    __syncthreads();
    int base = blockIdx.x * 2048;
#pragma unroll
    for (int r = 0; r < 8; ++r) {
        int e = base + r * 256 + t;
        if (e < NE) atomicAdd(&lcnt[ei[NE + e] >> 8], 1);
    }
    __syncthreads();
    for (int i = t; i < NBUCK; i += 256)
        lofs[i] = lcnt[i] ? atomicAdd(&curA[i], lcnt[i]) : 0;
    __syncthreads();
#pragma unroll
    for (int r = 0; r < 8; ++r) {
        int e = base + r * 256 + t;
        if (e < NE) {
            int d = ei[NE + e];
            int p = atomicAdd(&lofs[d >> 8], 1);
            recA[p] = ((unsigned)(d & 255) << 20) | (unsigned)e;
        }
    }
}

// ---- stage 2A: per-bucket 256-bin LDS counting sort -> dlist + off_all[d] ----
__global__ __launch_bounds__(256) void sort_localA(const unsigned* __restrict__ recA,
                                                   const int* __restrict__ baseA,
                                                   int* __restrict__ off_all,
                                                   unsigned* __restrict__ dlist)
{
    __shared__ int c[256];
    __shared__ int live[256];
    int t = threadIdx.x;
    int b = blockIdx.x;
    int lo = baseA[b], hi = baseA[b + 1];
    c[t] = 0;
    __syncthreads();
    for (int i = lo + t; i < hi; i += 256)
        atomicAdd(&c[(recA[i] >> 20) & 255], 1);
    __syncthreads();
#pragma unroll
    for (int dd = 1; dd < 256; dd <<= 1) {
        int v = (t >= dd) ? c[t - dd] : 0;
        __syncthreads();
        c[t] += v;
        __syncthreads();
    }
    int ex = (t > 0) ? c[t - 1] : 0;          // exclusive within-bucket prefix
    int d = (b << 8) + t;
    if (d <= NN) off_all[d] = lo + ex;        // d==NN hits b=195,t=80 -> NE
    live[t] = lo + ex;
    __syncthreads();
    for (int i = lo + t; i < hi; i += 256) {
        unsigned rec = recA[i];
        int pos = atomicAdd(&live[(rec >> 20) & 255], 1);
        dlist[pos] = rec & 0xFFFFFu;          // e at dst-sorted position (dp)
    }
}

// ---- stage 1B: scatter (s&255, dp, e) into src-buckets; s from random read ----
__global__ __launch_bounds__(256) void sort_scatterB(const int* __restrict__ ei,
                                                     const unsigned* __restrict__ dlist,
                                                     int* __restrict__ curB,
                                                     unsigned long long* __restrict__ recB)
{
    __shared__ int lcnt[NBUCK];
    __shared__ int lofs[NBUCK];
    __shared__ unsigned short sS[2048];
    __shared__ unsigned eS[2048];
    int t = threadIdx.x;
    for (int i = t; i < NBUCK; i += 256) lcnt[i] = 0;
    __syncthreads();
    int base = blockIdx.x * 2048;
#pragma unroll
    for (int r = 0; r < 8; ++r) {
        int dp = base + r * 256 + t;
        int li = r * 256 + t;
        if (dp < NE) {
            unsigned e = dlist[dp];
            int s = ei[e];                    // random 4B read (L2/L3-resident)
            sS[li] = (unsigned short)s;
            eS[li] = e;
            atomicAdd(&lcnt[s >> 8], 1);
        }
    }
    __syncthreads();
    for (int i = t; i < NBUCK; i += 256)
        lofs[i] = lcnt[i] ? atomicAdd(&curB[i], lcnt[i]) : 0;
    __syncthreads();
#pragma unroll
    for (int r = 0; r < 8; ++r) {
        int dp = base + r * 256 + t;
        int li = r * 256 + t;
        if (dp < NE) {
            int s = sS[li];
            unsigned e = eS[li];
            int p = atomicAdd(&lofs[s >> 8], 1);
            recB[p] = ((unsigned long long)(s & 255) << 40)
                    | ((unsigned long long)(unsigned)dp << 20)
                    | (unsigned long long)e;
        }
    }
}

// ---- stage 2B: per-bucket sort by s&255 -> sperm64 (same format) + src offs ----
__global__ __launch_bounds__(256) void sort_localB(const unsigned long long* __restrict__ recB,
                                                   const int* __restrict__ baseB,
                                                   int* __restrict__ off_all,
                                                   unsigned long long* __restrict__ sperm64)
{
    __shared__ int c[256];
    __shared__ int live[256];
    int t = threadIdx.x;
    int b = blockIdx.x;
    int lo = baseB[b], hi = baseB[b + 1];
    c[t] = 0;
    __syncthreads();
    for (int i = lo + t; i < hi; i += 256)
        atomicAdd(&c[(int)(recB[i] >> 40) & 255], 1);
    __syncthreads();
#pragma unroll
    for (int dd = 1; dd < 256; dd <<= 1) {
        int v = (t >= dd) ? c[t - dd] : 0;
        __syncthreads();
        c[t] += v;
        __syncthreads();
    }
    int ex = (t > 0) ? c[t - 1] : 0;
    int s = (b << 8) + t;
    if (s <= NN) off_all[NN + s] = NE + lo + ex;   // matches old off_all layout
    live[t] = lo + ex;
    __syncthreads();
    for (int i = lo + t; i < hi; i += 256) {
        unsigned long long rec = recB[i];
        int k = (int)(rec >> 40) & 255;
        int pos = atomicAdd(&live[k], 1);
        int sl = ((b << 8) + k) & 15;
        sperm64[pos] = ((unsigned long long)sl << 40) | (rec & 0xFFFFFFFFFFull);
    }
}

// ===========================================================================
// edge_fusedG<DIN>: UNCHANGED. block = out-edges of src nodes [16b,16b+16).
// ===========================================================================
template<int DIN>
__global__ __launch_bounds__(256) void edge_fusedG(
        const float* __restrict__ xin,    // [NN][DIN]
        const unsigned long long* __restrict__ sperm64, // [NE] src-sorted
        const float* __restrict__ ea,     // [NE][4] original order
        const float* __restrict__ eW1,    // [4][16]
        const float* __restrict__ eb1,    // [16]
        const float* __restrict__ eW2,    // [16][DIN*16]
        const float* __restrict__ eb2,    // [DIN*16]
        const int*   __restrict__ off_all,// src CSR at off_all[NN+s]
        __half* __restrict__ msgbuf)      // [NE][16] fp16 dst-sorted rows
{
    constexpr int MROW = 260;
    constexpr int W2B  = DIN * 16 * 20 * 4;           // w2L bytes (phase 1)
    constexpr int SMB  = 16 * MROW * 4 + 256 * 4;     // smemM + sdp (phase 2)
    constexpr int UNIB = (W2B > SMB) ? W2B : SMB;
    __shared__ __align__(16) char uni[UNIB];
    float* w2L   = (float*)uni;                        // [(i*16+k)*20 + o]
    float* smemM = (float*)uni;                        // [16][MROW]
    int*   sdp   = (int*)(uni + 16 * MROW * 4);        // [256]
    __shared__ __align__(16) float4 G4[16 * 69];       // [sl*69 + ob*17 + k]
    __shared__ __align__(16) float4 xbL[16 * 5];       // [sl*5 + ob] (pad 5)
    __shared__ __align__(16) float  xL[16 * DIN];
    __shared__ __align__(16) float  b2L[DIN * 16];
    __shared__ __align__(16) float4 w1t[16];
    __shared__ __align__(16) float  b1s[16];

    int tid = threadIdx.x;
    int nb  = blockIdx.x * 16;                // first src node of block
    if (tid < 16) {
        w1t[tid] = make_float4(eW1[tid], eW1[16 + tid], eW1[32 + tid], eW1[48 + tid]);
        b1s[tid] = eb1[tid];
    }
    for (int t = tid; t < 16 * DIN * 16; t += 256) {
        int k = t / (DIN * 16);
        int rem = t - k * DIN * 16;
        int i = rem >> 4, o = rem & 15;
        w2L[(i * 16 + k) * 20 + o] = eW2[t];
    }
    for (int t = tid; t < DIN * 16; t += 256) b2L[t] = eb2[t];
    for (int t = tid; t < 16 * DIN; t += 256) xL[t] = xin[(size_t)nb * DIN + t];
    __syncthreads();

    // ---- phase 1: G + xb for 16 local nodes; thread (nl, k) ----
    {
        int nl = tid >> 4, k = tid & 15;
        const float* xrow = xL + nl * DIN;
#pragma unroll
        for (int ob = 0; ob < 4; ++ob) {
            float4 a4 = make_float4(0.f, 0.f, 0.f, 0.f);
#pragma unroll
            for (int i = 0; i < DIN; ++i) {
                const float4 w = *((const float4*)(w2L + (i * 16 + k) * 20) + ob);
                a4.x += xrow[i] * w.x; a4.y += xrow[i] * w.y;
                a4.z += xrow[i] * w.z; a4.w += xrow[i] * w.w;
            }
            G4[nl * 69 + ob * 17 + k] = a4;
        }
        if (k < 4) {
            int ob = k;
            const float4* b2v = (const float4*)b2L;
            float4 a4 = make_float4(0.f, 0.f, 0.f, 0.f);
#pragma unroll
            for (int i = 0; i < DIN; ++i) {
                float4 b = b2v[i * 4 + ob];
                a4.x += xrow[i] * b.x; a4.y += xrow[i] * b.y;
                a4.z += xrow[i] * b.z; a4.w += xrow[i] * b.w;
            }
            xbL[nl * 5 + ob] = a4;
        }
    }
    __syncthreads();   // w2L dead; uni becomes smemM/sdp

    // ---- phase 2: chunked edge loop over this block's src-CSR range ----
    int eBeg = off_all[NN + nb] - NE;
    int eEnd = off_all[NN + nb + 16] - NE;
    for (int cb = eBeg; cb < eEnd; cb += 256) {
        int pos = cb + tid;
        bool valid = pos < eEnd;
        unsigned long long pk = valid ? sperm64[pos] : 0ull;
        int e  = (int)(pk & 0xFFFFFu);
        int dp = (int)((pk >> 20) & 0xFFFFFu);
        int sl = (int)(pk >> 40);
        float4 a = valid ? ((const float4*)ea)[e] : make_float4(0.f, 0.f, 0.f, 0.f);

        float h[16];
#pragma unroll
        for (int j = 0; j < 16; ++j) {
            float4 w = w1t[j];
            float p = b1s[j] + a.x * w.x + a.y * w.y + a.z * w.z + a.w * w.w;
            h[j] = p * sigm(p);
        }
        float4 acc[4];
#pragma unroll
        for (int ob = 0; ob < 4; ++ob) acc[ob] = xbL[sl * 5 + ob];
#pragma unroll
        for (int k = 0; k < 16; ++k) {
            float hk = h[k];
#pragma unroll
            for (int ob = 0; ob < 4; ++ob) {
                float4 g = G4[sl * 69 + ob * 17 + k];
                acc[ob].x += hk * g.x; acc[ob].y += hk * g.y;
                acc[ob].z += hk * g.z; acc[ob].w += hk * g.w;
            }
        }
        sdp[tid] = valid ? dp : -1;
#pragma unroll
        for (int ob = 0; ob < 4; ++ob) {
            smemM[(ob * 4 + 0) * MROW + tid] = acc[ob].x;
            smemM[(ob * 4 + 1) * MROW + tid] = acc[ob].y;
            smemM[(ob * 4 + 2) * MROW + tid] = acc[ob].z;
            smemM[(ob * 4 + 3) * MROW + tid] = acc[ob].w;
        }
        __syncthreads();
        // 8 lanes per row: lane packs channels (2p, 2p+1) into one __half2.
#pragma unroll
        for (int r = 0; r < 8; ++r) {
            int le = r * 32 + (tid >> 3);          // 32 rows per round
            int p  = tid & 7;
            int d2 = sdp[le];                      // 8-lane broadcast
            float v0 = smemM[(2 * p)     * MROW + le];
            float v1 = smemM[(2 * p + 1) * MROW + le];
            if (d2 >= 0) {
                __half2 hv = __floats2half2_rn(v0, v1);
                *((__half2*)(msgbuf + (size_t)d2 * 16) + p) = hv;  // 32B rows
            }
        }
        __syncthreads();
    }
}

// ===========================================================================
// Gather helper: UNCHANGED.
// ===========================================================================
__device__ __forceinline__ float gather_msg16(const __half* __restrict__ msgbuf,
                                              int s0, int e0, int tid)
{
    int half = (tid >> 3) & 1;
    int p    = tid & 7;
    float ax = 0.f, ay = 0.f;
    for (int j = s0 + half; j < e0; j += 2) {
        __half2 hv = *((const __half2*)(msgbuf + (size_t)j * 16) + p);
        float2 f = __half22float2(hv);
        ax += f.x; ay += f.y;
    }
    ax += __shfl_xor(ax, 8, 16);
    ay += __shfl_xor(ay, 8, 16);
    int ch = tid & 15;
    float vx = __shfl(ax, ch >> 1, 16);
    float vy = __shfl(ay, ch >> 1, 16);
    return (ch & 1) ? vy : vx;
}

__global__ __launch_bounds__(256) void gather_L0(
        const float* __restrict__ xin,    // [NN][8]
        const float* __restrict__ root,   // [8][16]
        const float* __restrict__ bias,   // [16]
        const int*   __restrict__ off_all,
        const __half* __restrict__ msgbuf,
        float* __restrict__ x1)           // [NN][16]
{
    __shared__ __align__(16) float rootL[8 * 16];
    __shared__ __align__(16) float biasL[16];
    int tid = threadIdx.x;
    if (tid < 128) rootL[tid] = root[tid];
    if (tid < 16) biasL[tid] = bias[tid];
    __syncthreads();

    int ch = tid & 15;
    int n  = blockIdx.x * 16 + (tid >> 4);
    int s0 = off_all[n], e0 = off_all[n + 1];

    float acc = gather_msg16(msgbuf, s0, e0, tid);
    float v = acc / fmaxf((float)(e0 - s0), 1.0f) + biasL[ch];
#pragma unroll
    for (int i = 0; i < 8; ++i)
        v += xin[(size_t)n * 8 + i] * rootL[i * 16 + ch];
    x1[(size_t)n * 16 + ch] = fmaxf(v, 0.f);
}

__global__ __launch_bounds__(256) void gather_final(
        const float* __restrict__ x1,     // [NN][16]
        const float* __restrict__ root,   // [16][16]
        const float* __restrict__ bias,   // [16]
        const int*   __restrict__ off_all,
        const __half* __restrict__ msgbuf,
        const float* __restrict__ mW1,    // [16][16]
        const float* __restrict__ mb1,    // [16]
        const float* __restrict__ mW2,    // [16]
        const float* __restrict__ mb2,    // [1]
        float* __restrict__ out)          // [NN]
{
    __shared__ __align__(16) float rootL[256];
    __shared__ __align__(16) float biasL[16];
    __shared__ __align__(16) float w1m[256];
    __shared__ __align__(16) float b1m[16];
    __shared__ __align__(16) float w2m[16];
    __shared__ float b2m;
    int tid = threadIdx.x;
    rootL[tid] = root[tid];
    w1m[tid] = mW1[tid];
    if (tid < 16) { biasL[tid] = bias[tid]; b1m[tid] = mb1[tid]; w2m[tid] = mW2[tid]; }
    if (tid == 0) b2m = mb2[0];
    __syncthreads();

    int ch = tid & 15;
    int n  = blockIdx.x * 16 + (tid >> 4);
    int s0 = off_all[n], e0 = off_all[n + 1];

    float acc = gather_msg16(msgbuf, s0, e0, tid);
    float v = acc / fmaxf((float)(e0 - s0), 1.0f) + biasL[ch];
#pragma unroll
    for (int i = 0; i < 16; ++i)
        v += x1[(size_t)n * 16 + i] * rootL[i * 16 + ch];
    v = fmaxf(v, 0.f);

    float z = b1m[ch];
#pragma unroll
    for (int o = 0; o < 16; ++o) {
        float vo = __shfl(v, o, 16);
        z += vo * w1m[o * 16 + ch];
    }
    float ss = z * sigm(z) * w2m[ch];
#pragma unroll
    for (int off = 8; off; off >>= 1) ss += __shfl_xor(ss, off, 16);
    if (ch == 0) out[n] = sigm(ss + b2m);
}

// ===========================================================================
// Host launch
// ===========================================================================
extern "C" void kernel_launch(void* const* d_in, const int* in_sizes, int n_in,
                              void* d_out, int out_size, void* d_ws, size_t ws_size,
                              hipStream_t stream) {
    const float* x     = (const float*)d_in[0];
    const int*   ei    = (const int*)  d_in[1];
    const float* ea    = (const float*)d_in[2];
    const float* eW1_0 = (const float*)d_in[3];
    const float* eb1_0 = (const float*)d_in[4];
    const float* eW2_0 = (const float*)d_in[5];
    const float* eb2_0 = (const float*)d_in[6];
    const float* root0 = (const float*)d_in[7];
    const float* bias0 = (const float*)d_in[8];
    const float* eW1_1 = (const float*)d_in[9];
    const float* eb1_1 = (const float*)d_in[10];
    const float* eW2_1 = (const float*)d_in[11];
    const float* eb2_1 = (const float*)d_in[12];
    const float* root1 = (const float*)d_in[13];
    const float* bias1 = (const float*)d_in[14];
    const float* mW1   = (const float*)d_in[15];
    const float* mb1   = (const float*)d_in[16];
    const float* mW2   = (const float*)d_in[17];
    const float* mb2   = (const float*)d_in[18];
    float* out = (float*)d_out;

    const int GG  = NN / 16;                 // 3125
    const int SBK = (NE + 2047) / 2048;      // 391 blocks for stage0/1

    // ---- ws layout (4B words) ----
    int* W = (int*)d_ws;
    int* off_all = W;                        // [0, 100004)
    int* cntA    = W + 100004;               // 256
    int* cntB    = W + 100260;               // 256
    int* baseA   = W + 100516;               // 200 (197 used)
    int* baseB   = W + 100716;               // 200
    int* curA    = W + 100916;               // 256
    int* curB    = W + 101172;               // 256 -> ends 101428, pad to 101440
    unsigned long long* sperm64 = (unsigned long long*)(W + 101440); // NE u64
    float*  x1     = (float*)(W + 1701440);  // [NN][16]
    __half* msgbuf = (__half*)(W + 2501440); // [NE][16] fp16 = 6.4M words
    // sort scratch overlaid on msgbuf region (dead before edge kernels run):
    unsigned* recA  = (unsigned*)(W + 2501440);            // NE u32
    unsigned* dlist = (unsigned*)(W + 3301440);            // NE u32
    unsigned long long* recB = (unsigned long long*)(W + 4101440); // NE u64

    hipMemsetAsync(cntA, 0, 512 * sizeof(int), stream);   // cntA + cntB
    sort_count   <<<SBK,   256, 0, stream>>>(ei, cntA, cntB);
    sort_scan    <<<1,     256, 0, stream>>>(cntA, cntB, baseA, baseB, curA, curB);
    sort_scatterA<<<SBK,   256, 0, stream>>>(ei, curA, recA);
    sort_localA  <<<NBUCK, 256, 0, stream>>>(recA, baseA, off_all, dlist);
    sort_scatterB<<<SBK,   256, 0, stream>>>(ei, dlist, curB, recB);
    sort_localB  <<<NBUCK, 256, 0, stream>>>(recB, baseB, off_all, sperm64);

    // ---- layer 0 ----
    edge_fusedG<8><<<GG, 256, 0, stream>>>(x, sperm64, ea, eW1_0, eb1_0,
                                           eW2_0, eb2_0, off_all, msgbuf);
    gather_L0<<<GG, 256, 0, stream>>>(x, root0, bias0, off_all, msgbuf, x1);

    // ---- layer 1 ----
    edge_fusedG<16><<<GG, 256, 0, stream>>>(x1, sperm64, ea, eW1_1, eb1_1,
                                            eW2_1, eb2_1, off_all, msgbuf);
    gather_final<<<GG, 256, 0, stream>>>(x1, root1, bias1, off_all, msgbuf,
                                         mW1, mb1, mW2, mb2, out);
}